// Round 3
// baseline (20249.310 us; speedup 1.0000x reference)
//
#include <hip/hip_runtime.h>
#include <hip/hip_bf16.h>
#include <hip/hip_fp16.h>

// ---------------------------------------------------------------------------
// ModelInstructionAggregate: token-LSTM (batch 8192, T<=16) -> sequential
// instruction-LSTM (8192 steps, batch 1) -> Linear(256->1).
// Round 6: k_seq_lstm -> k_seq4, a 4-workgroup (4-CU) cooperative kernel.
//   Rationale: rounds 3-5 proved the RA will not keep 192 weight-half2 per
//   thread in arch VGPRs (VGPR_Count pinned at 128; VALUBusy ~71% of the CU
//   = per-dot AGPR/scratch copy tax). Splitting the 1024x256 matvec across
//   4 CUs cuts weights to 64 half2/thread -> fits the 128-reg budget the
//   compiler already grants. Cross-WG h exchange via device-scope atomics
//   (OK cross-XCD, m20), double-buffered slices (depth-2 ring, skew<=1 is
//   structural), spin-wait on per-WG step flags. Single dispatch grid=4 ->
//   co-resident. Sync area lives in the embeds workspace region (dead after
//   k_xi), zeroed by a stream-ordered hipMemsetAsync before k_seq4.
// ---------------------------------------------------------------------------

constexpr int H_ = 256;    // hidden
constexpr int T_ = 16;     // max token steps
constexpr int N_ = 8192;   // instructions
constexpr int BI = 16;     // instructions per block in batched kernels

typedef _Float16 half_t;
typedef half_t half2_t __attribute__((ext_vector_type(2)));

#if __has_builtin(__builtin_amdgcn_fdot2)
#define FDOT2(w, h, acc) __builtin_amdgcn_fdot2((w), (h), (acc), false)
#else
__device__ __forceinline__ float fdot2_emul(half2_t w, half2_t h, float acc) {
    return acc + (float)w.x * (float)h.x + (float)w.y * (float)h.y;
}
#define FDOT2(w, h, acc) fdot2_emul((w), (h), (acc))
#endif

__device__ __forceinline__ float sigmoidf_(float x) {
    return 1.0f / (1.0f + __expf(-x));
}
__device__ __forceinline__ float tanhf_(float x) {
    return 2.0f / (1.0f + __expf(-2.0f * x)) - 1.0f;
}

// lane <-> lane^1 swap via DPP quad_perm {1,0,3,2} (ctrl=0xB1), 1 VALU inst.
__device__ __forceinline__ float dpp_swap1(float x) {
    int xi = __builtin_bit_cast(int, x);
    int r = __builtin_amdgcn_update_dpp(0, xi, 0xB1, 0xF, 0xF, true);
    return __builtin_bit_cast(float, r);
}

// --------------------------- weight transposes -----------------------------
__global__ __launch_bounds__(256) void k_transpose_cat(
    const float* __restrict__ Wih, const float* __restrict__ Whh,
    float4* __restrict__ Wt)
{
    int tid = blockIdx.x * 256 + threadIdx.x;      // 1024 rows * 128 kb
    int kb = tid & 127, row = tid >> 7;
    float4 v = (kb < 64) ? ((const float4*)Wih)[row * 64 + kb]
                         : ((const float4*)Whh)[row * 64 + (kb - 64)];
    Wt[kb * 1024 + row] = v;
}

__global__ __launch_bounds__(256) void k_transpose_i(
    const float* __restrict__ Wsrc, float4* __restrict__ Wt)
{
    int tid = blockIdx.x * 256 + threadIdx.x;      // 1024 rows * 64 kb
    int kb = tid & 63, row = tid >> 6;
    Wt[kb * 1024 + row] = ((const float4*)Wsrc)[row * 64 + kb];
}

// ----------------------- phase 1: batched token LSTM -----------------------
__global__ __launch_bounds__(256, 4) void k_token_lstm(
    const float* __restrict__ tokens, const int* __restrict__ lengths,
    const float4* __restrict__ Wt,   // [128][1024] float4 (x-part then h-part)
    const float* __restrict__ bih, const float* __restrict__ bhh,
    float* __restrict__ embeds)      // [N_][H_]
{
    __shared__ __align__(16) float xs[BI][H_];
    __shared__ __align__(16) float hs[BI][H_];
    __shared__ __align__(16) float cs[BI][H_];
    __shared__ int len[BI];

    const int j = threadIdx.x;
    const int n0 = blockIdx.x * BI;
    if (j < BI) len[j] = lengths[n0 + j];
#pragma unroll
    for (int i = 0; i < BI; ++i) { hs[i][j] = 0.f; cs[i][j] = 0.f; }
    const float b0 = bih[j]       + bhh[j];
    const float b1 = bih[256 + j] + bhh[256 + j];
    const float b2 = bih[512 + j] + bhh[512 + j];
    const float b3 = bih[768 + j] + bhh[768 + j];
    __syncthreads();

    for (int t = 0; t < T_; ++t) {
#pragma unroll
        for (int q = 0; q < 4; ++q) {
            int idx = j + q * 256;
            int i = idx >> 6, e4 = idx & 63;
            ((float4*)xs)[i * 64 + e4] =
                ((const float4*)tokens)[((size_t)(n0 + i) * T_ + t) * 64 + e4];
        }
        __syncthreads();

        float a0[BI], a1[BI], a2[BI], a3[BI];
#pragma unroll
        for (int i = 0; i < BI; ++i) { a0[i] = 0.f; a1[i] = 0.f; a2[i] = 0.f; a3[i] = 0.f; }

        for (int kb = 0; kb < 64; ++kb) {
            float4 w0 = Wt[kb * 1024 + j];
            float4 w1 = Wt[kb * 1024 + 256 + j];
            float4 w2 = Wt[kb * 1024 + 512 + j];
            float4 w3 = Wt[kb * 1024 + 768 + j];
#pragma unroll
            for (int i = 0; i < BI; ++i) {
                float4 x4 = ((const float4*)xs)[i * 64 + kb];
                a0[i] += w0.x * x4.x + w0.y * x4.y + w0.z * x4.z + w0.w * x4.w;
                a1[i] += w1.x * x4.x + w1.y * x4.y + w1.z * x4.z + w1.w * x4.w;
                a2[i] += w2.x * x4.x + w2.y * x4.y + w2.z * x4.z + w2.w * x4.w;
                a3[i] += w3.x * x4.x + w3.y * x4.y + w3.z * x4.z + w3.w * x4.w;
            }
        }
        for (int kb = 0; kb < 64; ++kb) {
            float4 w0 = Wt[(64 + kb) * 1024 + j];
            float4 w1 = Wt[(64 + kb) * 1024 + 256 + j];
            float4 w2 = Wt[(64 + kb) * 1024 + 512 + j];
            float4 w3 = Wt[(64 + kb) * 1024 + 768 + j];
#pragma unroll
            for (int i = 0; i < BI; ++i) {
                float4 h4 = ((const float4*)hs)[i * 64 + kb];
                a0[i] += w0.x * h4.x + w0.y * h4.y + w0.z * h4.z + w0.w * h4.w;
                a1[i] += w1.x * h4.x + w1.y * h4.y + w1.z * h4.z + w1.w * h4.w;
                a2[i] += w2.x * h4.x + w2.y * h4.y + w2.z * h4.z + w2.w * h4.w;
                a3[i] += w3.x * h4.x + w3.y * h4.y + w3.z * h4.z + w3.w * h4.w;
            }
        }
        __syncthreads();

#pragma unroll
        for (int i = 0; i < BI; ++i) {
            if (t < len[i]) {
                float gi = sigmoidf_(a0[i] + b0);
                float gf = sigmoidf_(a1[i] + b1);
                float gg = tanhf_   (a2[i] + b2);
                float go = sigmoidf_(a3[i] + b3);
                float c2 = gf * cs[i][j] + gi * gg;
                cs[i][j] = c2;
                hs[i][j] = go * tanhf_(c2);
            }
        }
    }
#pragma unroll
    for (int i = 0; i < BI; ++i)
        embeds[(size_t)(n0 + i) * H_ + j] = hs[i][j];
}

// --------------------- phase 2a: XI = embeds @ Wih_i^T + b ------------------
__global__ __launch_bounds__(256, 4) void k_xi(
    const float* __restrict__ embeds, const float4* __restrict__ WiT, // [64][1024]
    const float* __restrict__ bih, const float* __restrict__ bhh,
    float* __restrict__ XI)          // [N_][1024]
{
    __shared__ __align__(16) float xs[BI][H_];
    const int j = threadIdx.x;
    const int n0 = blockIdx.x * BI;
#pragma unroll
    for (int q = 0; q < 4; ++q) {
        int idx = j + q * 256;
        int i = idx >> 6, e4 = idx & 63;
        ((float4*)xs)[i * 64 + e4] = ((const float4*)embeds)[(size_t)(n0 + i) * 64 + e4];
    }
    const float b0 = bih[j]       + bhh[j];
    const float b1 = bih[256 + j] + bhh[256 + j];
    const float b2 = bih[512 + j] + bhh[512 + j];
    const float b3 = bih[768 + j] + bhh[768 + j];
    __syncthreads();

    float a0[BI], a1[BI], a2[BI], a3[BI];
#pragma unroll
    for (int i = 0; i < BI; ++i) { a0[i] = 0.f; a1[i] = 0.f; a2[i] = 0.f; a3[i] = 0.f; }

    for (int kb = 0; kb < 64; ++kb) {
        float4 w0 = WiT[kb * 1024 + j];
        float4 w1 = WiT[kb * 1024 + 256 + j];
        float4 w2 = WiT[kb * 1024 + 512 + j];
        float4 w3 = WiT[kb * 1024 + 768 + j];
#pragma unroll
        for (int i = 0; i < BI; ++i) {
            float4 x4 = ((const float4*)xs)[i * 64 + kb];
            a0[i] += w0.x * x4.x + w0.y * x4.y + w0.z * x4.z + w0.w * x4.w;
            a1[i] += w1.x * x4.x + w1.y * x4.y + w1.z * x4.z + w1.w * x4.w;
            a2[i] += w2.x * x4.x + w2.y * x4.y + w2.z * x4.z + w2.w * x4.w;
            a3[i] += w3.x * x4.x + w3.y * x4.y + w3.z * x4.z + w3.w * x4.w;
        }
    }
#pragma unroll
    for (int i = 0; i < BI; ++i) {
        size_t base = (size_t)(n0 + i) * 1024;
        XI[base + j]       = a0[i] + b0;
        XI[base + 256 + j] = a1[i] + b1;
        XI[base + 512 + j] = a2[i] + b2;
        XI[base + 768 + j] = a3[i] + b3;
    }
}

// ----------------- phase 2b: 4-CU cooperative sequential LSTM --------------
// grid=4 (single dispatch => co-resident), 512 threads each.
// WG g owns h-units [64g, 64g+64) i.e. gate rows gate*256 + 64g + ul.
// Thread j: p=j&1 (k-half), t=j>>1 (row 0..255), gate=t>>6, ul=t&63.
// Weights: 64 half2 per thread, ARCH VGPRs (fits the 128-reg budget).
// h: f16, LDS double-buffered [2][256]; step exchange of 64-unit slices via
// device-scope atomics (slab [2][4][32]u32 + per-WG step flags).
__global__ __launch_bounds__(512)
void k_seq4(
    const float* __restrict__ XI,    // [N_][1024]
    const float* __restrict__ Whh,   // [1024][256]
    float* __restrict__ outs,        // [N_][H_]
    unsigned* __restrict__ sync)     // flags at +0 (stride 64 u32), slab at +1024 u32
{
    __shared__ __align__(16) half2_t hbuf[2][128];   // h as f16, double-buffered
    __shared__ float gates[256];

    const int g    = blockIdx.x;            // 0..3
    const int j    = threadIdx.x;           // 0..511
    const int p    = j & 1;                 // k-half
    const int t    = j >> 1;                // row index within WG
    const int gate = t >> 6, ul = t & 63;
    const int rowoff = gate * 256 + g * 64 + ul;   // global gate row / XI index

    unsigned* slab = sync + 1024;           // [2][4][32] u32

    // ---- weights -> 64 arch-VGPR half2 (k-half p of row rowoff) ----
    half2_t w[64];
    {
        const float4* wr = (const float4*)(Whh + (size_t)rowoff * 256 + p * 128);
#pragma unroll
        for (int q = 0; q < 32; ++q) {
            float4 v = wr[q];
            w[2 * q]     = half2_t{(half_t)v.x, (half_t)v.y};
            w[2 * q + 1] = half2_t{(half_t)v.z, (half_t)v.w};
        }
    }
    if (j < 128) ((unsigned*)hbuf)[j] = 0u;          // hbuf[0] = h_0 = 0
    __syncthreads();

    float c  = 0.f;                                   // unit state (threads j<64)
    float xi = (p == 0) ? XI[rowoff] : 0.f;

    for (int n = 0; n < N_; ++n) {
        const int nb = (n + 1) & 1;
        const int nn = (n + 1 < N_) ? (n + 1) : n;    // xi prefetch (hidden under dots)
        float xin = (p == 0) ? XI[(size_t)nn * 1024 + rowoff] : 0.f;

        // ---- gate dot: 64 fdot2 over k-half p; h reads are 2-addr LDS bcast
        const float4* hv4 = ((const float4*)(hbuf[n & 1])) + p * 16;
        float acc = 0.f, accb = 0.f;
#pragma unroll
        for (int q = 0; q < 16; ++q) {
            float4 hx = hv4[q];
            half2_t h0 = __builtin_bit_cast(half2_t, hx.x);
            half2_t h1 = __builtin_bit_cast(half2_t, hx.y);
            half2_t h2 = __builtin_bit_cast(half2_t, hx.z);
            half2_t h3 = __builtin_bit_cast(half2_t, hx.w);
            acc  = FDOT2(w[4 * q + 0], h0, acc);
            accb = FDOT2(w[4 * q + 1], h1, accb);
            acc  = FDOT2(w[4 * q + 2], h2, acc);
            accb = FDOT2(w[4 * q + 3], h3, accb);
        }
        float s = acc + accb;
        float full = s + dpp_swap1(s);                // pair-reduce k-halves
        if (p == 0) gates[t] = full + xi;
        __syncthreads();

        if (j < 64) {
            // ---- own 64-unit nonlinearity + publish (wave 0) ----
            float gi = sigmoidf_(gates[j]);
            float gf = sigmoidf_(gates[64 + j]);
            float gg = tanhf_   (gates[128 + j]);
            float go = sigmoidf_(gates[192 + j]);
            float c2 = gf * c + gi * gg;
            c = c2;
            float h2n = go * tanhf_(c2);
            outs[(size_t)n * H_ + g * 64 + j] = h2n;

            unsigned hb = (unsigned)__builtin_bit_cast(unsigned short, (half_t)h2n);
            ((unsigned short*)(hbuf[nb]))[g * 64 + j] = (unsigned short)hb;  // local h
            unsigned lo = (unsigned)__shfl((int)hb, 2 * j, 64);
            unsigned hi = (unsigned)__shfl((int)hb, 2 * j + 1, 64);
            if (j < 32) {
                unsigned val = (lo & 0xffffu) | (hi << 16);
                __hip_atomic_store(&slab[nb * 128 + g * 32 + j], val,
                                   __ATOMIC_RELAXED, __HIP_MEMORY_SCOPE_AGENT);
            }
            if (j == 0)   // release orders the wave's slab stores (vmcnt drain)
                __hip_atomic_store(&sync[g * 64], (unsigned)(n + 1),
                                   __ATOMIC_RELEASE, __HIP_MEMORY_SCOPE_AGENT);
        } else if (j >= 256 && j < 352) {
            // ---- fetch 3 remote slices (waves 4-5) ----
            const int o   = (j - 256) >> 5;           // 0..2
            const int go_ = o + (o >= g ? 1 : 0);     // remote WG id
            const int idx = (j - 256) & 31;
            unsigned* fp = &sync[go_ * 64];
            while (__hip_atomic_load(fp, __ATOMIC_ACQUIRE,
                                     __HIP_MEMORY_SCOPE_AGENT) < (unsigned)(n + 1))
                __builtin_amdgcn_s_sleep(1);
            unsigned v = __hip_atomic_load(&slab[nb * 128 + go_ * 32 + idx],
                                           __ATOMIC_RELAXED, __HIP_MEMORY_SCOPE_AGENT);
            ((unsigned*)(hbuf[nb]))[go_ * 32 + idx] = v;
        }
        __syncthreads();                              // hbuf[nb] complete
        xi = xin;
    }
}

// ------------------------- final linear head -------------------------------
__global__ __launch_bounds__(256) void k_final(
    const float* __restrict__ outs, const float* __restrict__ Wl,
    const float* __restrict__ bl, float* __restrict__ y)
{
    const int lane = threadIdx.x & 63;
    const int g = threadIdx.x >> 6;
    const int n = blockIdx.x * 4 + g;
    const float* row = outs + (size_t)n * H_;
    float s = row[lane] * Wl[lane] + row[64 + lane] * Wl[64 + lane]
            + row[128 + lane] * Wl[128 + lane] + row[192 + lane] * Wl[192 + lane];
#pragma unroll
    for (int off = 32; off > 0; off >>= 1) s += __shfl_down(s, off, 64);
    if (lane == 0) y[n] = s + bl[0];
}

// ---------------------------------------------------------------------------
extern "C" void kernel_launch(void* const* d_in, const int* in_sizes, int n_in,
                              void* d_out, int out_size, void* d_ws, size_t ws_size,
                              hipStream_t stream)
{
    const float* tokens = (const float*)d_in[0];
    const int*   lengths= (const int*)  d_in[1];
    const float* Wih_t  = (const float*)d_in[2];
    const float* Whh_t  = (const float*)d_in[3];
    const float* bih_t  = (const float*)d_in[4];
    const float* bhh_t  = (const float*)d_in[5];
    const float* Wih_i  = (const float*)d_in[6];
    const float* Whh_i  = (const float*)d_in[7];
    const float* bih_i  = (const float*)d_in[8];
    const float* bhh_i  = (const float*)d_in[9];
    const float* Wl     = (const float*)d_in[10];
    const float* bl     = (const float*)d_in[11];
    float* out = (float*)d_out;

    char* ws = (char*)d_ws;
    float*  embeds = (float*) (ws);                                // 8 MB (dead after k_xi)
    float*  XI     = (float*) (ws + (size_t)8  * 1024 * 1024);     // 32 MB
    float*  outs   = (float*) (ws + (size_t)40 * 1024 * 1024);     // 8 MB
    float4* WcatT  = (float4*)(ws + (size_t)48 * 1024 * 1024);     // 2 MB
    float4* WiT    = (float4*)(ws + (size_t)50 * 1024 * 1024);     // 1 MB
    unsigned* syncA= (unsigned*)(ws);   // flags (1 KB) + slab (@4 KB), inside embeds

    k_transpose_cat<<<512,  256, 0, stream>>>(Wih_t, Whh_t, WcatT);
    k_transpose_i  <<<256,  256, 0, stream>>>(Wih_i, WiT);
    k_token_lstm   <<<512,  256, 0, stream>>>(tokens, lengths, WcatT, bih_t, bhh_t, embeds);
    k_xi           <<<512,  256, 0, stream>>>(embeds, WiT, bih_i, bhh_i, XI);
    // embeds is dead now; zero the sync flags (stream-ordered, graph-safe)
    (void)hipMemsetAsync(syncA, 0, 1024, stream);
    k_seq4         <<<4,    512, 0, stream>>>(XI, Whh_i, outs, syncA);
    k_final        <<<2048, 256, 0, stream>>>(outs, Wl, bl, out);
}